// Round 5
// baseline (184.905 us; speedup 1.0000x reference)
//
#include <hip/hip_runtime.h>
#include <math.h>

namespace {
constexpr int kB = 2, kN = 2048, kDim = 256, kH = 8, kDH = 32;
constexpr int kBH = kB * kH;
constexpr long kPlane = (long)kBH * kN * kDH;  // 1,048,576 elems per tensor
// DH^-0.5 / ln2 folded into stored q so softmax weight = exp2(score)
constexpr float kQScaleL2 = 0.25506852552f;
}

typedef unsigned short u16;
typedef short short8 __attribute__((ext_vector_type(8)));
typedef short short4v __attribute__((ext_vector_type(4)));
typedef float floatx16 __attribute__((ext_vector_type(16)));
#define MFMA_BF16(a, b, c) __builtin_amdgcn_mfma_f32_32x32x16_bf16(a, b, c, 0, 0, 0)

__device__ inline u16 bf16b(float x) {
    union { float f; unsigned u; } c; c.f = x;
    unsigned r = c.u + 0x7FFFu + ((c.u >> 16) & 1u);
    return (u16)(r >> 16);
}
__device__ inline unsigned pack2(float x, float y) {
    return (unsigned)bf16b(x) | ((unsigned)bf16b(y) << 16);
}
// truncating bf16 pack of two positive floats via one v_perm_b32
__device__ inline unsigned packtr(float lo, float hi) {
    return __builtin_amdgcn_perm(__float_as_uint(hi), __float_as_uint(lo), 0x07060302u);
}
__device__ inline short8 mk8(const float* e) {
    union { unsigned u[4]; short8 s; } c;
    c.u[0] = packtr(e[0], e[1]);
    c.u[1] = packtr(e[2], e[3]);
    c.u[2] = packtr(e[4], e[5]);
    c.u[3] = packtr(e[6], e[7]);
    return c.s;
}

// ---------------------------------------------------------------------------
// Build doubled/transposed bf16 weight matrices (unchanged).
// ---------------------------------------------------------------------------
__global__ __launch_bounds__(256, 2) void prep_w(
    const float* __restrict__ wq_r, const float* __restrict__ wq_i,
    const float* __restrict__ wkv_r, const float* __restrict__ wkv_i,
    const float* __restrict__ wo_r, const float* __restrict__ wo_i,
    u16* __restrict__ Wbig, u16* __restrict__ WoT)
{
    const long base = ((long)blockIdx.x * 256 + threadIdx.x) * 4;
    if (base < 786432) {
        const int c = (int)(base >> 9);
        const int k = (int)(base & 511);
        const int g = c >> 8, d = c & 255;
        const bool hi = k >= 256;
        const int k2 = hi ? k - 256 : k;
        const float* src;
        float sgn = 1.f;
        int col, stride;
        if (g < 2) {
            stride = 256; col = d;
            if (g == 0) { src = hi ? wq_i : wq_r; if (hi) sgn = -1.f; }
            else        { src = hi ? wq_r : wq_i; }
            sgn *= kQScaleL2;
        } else {
            stride = 512;
            col = (g >= 4) ? d + 256 : d;
            if ((g & 1) == 0) { src = hi ? wkv_i : wkv_r; if (hi) sgn = -1.f; }
            else              { src = hi ? wkv_r : wkv_i; }
        }
        short4v v;
        #pragma unroll
        for (int j = 0; j < 4; ++j)
            v[j] = (short)bf16b(src[(long)(k2 + j) * stride + col] * sgn);
        *(short4v*)(Wbig + base) = v;
    } else {
        const long o = base - 786432;
        const int c = (int)(o >> 9);
        const int k = (int)(o & 511);
        const bool hi = k >= 256;
        const int k2 = hi ? k - 256 : k;
        const float* src;
        float sgn = 1.f;
        int col;
        if (c < 256) { col = c;       src = hi ? wo_i : wo_r; if (hi) sgn = -1.f; }
        else         { col = c - 256; src = hi ? wo_r : wo_i; }
        short4v v;
        #pragma unroll
        for (int j = 0; j < 4; ++j)
            v[j] = (short)bf16b(src[(long)(k2 + j) * 256 + col] * sgn);
        *(short4v*)(WoT + o) = v;
    }
}

// ---------------------------------------------------------------------------
// QKV projection GEMM. vT stored [bh][32 d][2048 n] with n's bits 2<->3
// SWAPPED inside each 32-key group (PV B-frag permutation pre-applied).
// ---------------------------------------------------------------------------
__global__ __launch_bounds__(256, 2) void gemm_proj(
    const float* __restrict__ xr_g, const float* __restrict__ xi_g,
    const u16* __restrict__ BT,
    u16* __restrict__ qr, u16* __restrict__ qi, u16* __restrict__ kr,
    u16* __restrict__ ki, u16* __restrict__ vrT, u16* __restrict__ viT)
{
    __shared__ __align__(16) u16 sA[128 * 32];
    __shared__ __align__(16) u16 sB[128 * 32];
    const int tid = threadIdx.x;
    const int lane = tid & 63, l31 = lane & 31, lh = lane >> 5;
    const int w = tid >> 6, wrow = w & 1, wcol = w >> 1;
    const int srow = tid >> 2, sseg = tid & 3;
    const int n0 = blockIdx.x * 128, m0 = blockIdx.y * 128;

    floatx16 a00 = {0}, a01 = {0}, a10 = {0}, a11 = {0};

    for (int kt = 0; kt < 512; kt += 32) {
        __syncthreads();
        const float* xbase = (kt < 256) ? xr_g : xi_g;
        const int kc = (kt & 255) + sseg * 8;
        #pragma unroll
        for (int i = 0; i < 2; ++i) {
            const int r = srow + i * 64;
            {
                const float* src = xbase + (long)(m0 + r) * 256 + kc;
                const float4 f0 = *(const float4*)(src);
                const float4 f1 = *(const float4*)(src + 4);
                short8 v;
                v[0] = (short)bf16b(f0.x); v[1] = (short)bf16b(f0.y);
                v[2] = (short)bf16b(f0.z); v[3] = (short)bf16b(f0.w);
                v[4] = (short)bf16b(f1.x); v[5] = (short)bf16b(f1.y);
                v[6] = (short)bf16b(f1.z); v[7] = (short)bf16b(f1.w);
                *(short8*)(sA + r * 32 + sseg * 8) = v;
            }
            *(short8*)(sB + r * 32 + sseg * 8) =
                *(const short8*)(BT + (long)(n0 + r) * 512 + kt + sseg * 8);
        }
        __syncthreads();
        #pragma unroll
        for (int s = 0; s < 2; ++s) {
            const int ko = s * 16 + lh * 8;
            const short8 fa0 = *(const short8*)(sA + (wrow * 64 + l31) * 32 + ko);
            const short8 fa1 = *(const short8*)(sA + (wrow * 64 + 32 + l31) * 32 + ko);
            const short8 fb0 = *(const short8*)(sB + (wcol * 64 + l31) * 32 + ko);
            const short8 fb1 = *(const short8*)(sB + (wcol * 64 + 32 + l31) * 32 + ko);
            a00 = MFMA_BF16(fa0, fb0, a00);
            a01 = MFMA_BF16(fa0, fb1, a01);
            a10 = MFMA_BF16(fa1, fb0, a10);
            a11 = MFMA_BF16(fa1, fb1, a11);
        }
    }

    floatx16 accs[2][2] = {{a00, a01}, {a10, a11}};
    #pragma unroll
    for (int rt = 0; rt < 2; ++rt) {
        #pragma unroll
        for (int ct = 0; ct < 2; ++ct) {
            const int colb = n0 + wcol * 64 + ct * 32;
            const int g = colb >> 8;
            const int h = (colb & 255) >> 5;
            if (g < 4) {
                u16* pl = (g == 0) ? qr : (g == 1) ? qi : (g == 2) ? kr : ki;
                #pragma unroll
                for (int reg = 0; reg < 16; ++reg) {
                    const int row = m0 + wrow * 64 + rt * 32 + (reg & 3) + 8 * (reg >> 2) + 4 * lh;
                    const int b = row >> 11, nn = row & 2047;
                    pl[(((long)(b * 8 + h)) * 2048 + nn) * 32 + l31] = bf16b(accs[rt][ct][reg]);
                }
            } else {
                u16* pl = (g == 4) ? vrT : viT;
                #pragma unroll
                for (int reg = 0; reg < 16; ++reg) {
                    const int row = m0 + wrow * 64 + rt * 32 + (reg & 3) + 8 * (reg >> 2) + 4 * lh;
                    const int b = row >> 11, nn = row & 2047;
                    // pre-apply PV permutation: swap bits 2<->3 of n
                    const int np = (nn & ~12) | ((nn & 4) << 1) | ((nn & 8) >> 1);
                    pl[(((long)(b * 8 + h)) * 32 + l31) * 2048 + np] = bf16b(accs[rt][ct][reg]);
                }
            }
        }
    }
}

// ---------------------------------------------------------------------------
// MFMA flash attention v9: R2 replica-wave skeleton (K AND V LDS-staged --
// the R3/R4 lesson: K-from-global costs ~15us of vmcnt stall) widened to
// 64-KEY TILES. Each iteration carries two independent 32-key subtiles, so
// within one wave the matrix pipe (S_b, PV_a) overlaps the trans pipe
// (exp_a, exp_b) with no reliance on cross-wave scheduling, and the barrier
// count halves (64 -> 32). Denominator on VALU with 4 partial accumulators.
// setprio(1) around PV clusters only (m191). Merge tree unchanged.
// ---------------------------------------------------------------------------
__global__ __launch_bounds__(256, 3) void attn_kernel(
    const u16* __restrict__ qr_g, const u16* __restrict__ qi_g,
    const u16* __restrict__ kr_g, const u16* __restrict__ ki_g,
    const u16* __restrict__ vrT_g, const u16* __restrict__ viT_g,
    u16* __restrict__ xo)
{
    // [buf][Ka|Kb|Va|Vb][64 rows][40 pitch] = 40 KiB; merge scratch overlays
    __shared__ __align__(16) u16 smem[2][4][64 * 40];

    const int tid = threadIdx.x;
    const int lane = tid & 63, l31 = lane & 31, lh = lane >> 5;
    const int w = tid >> 6, ktype = w & 1, qtype = w >> 1;
    const int bh = blockIdx.x;          // bh = blockIdx.x: fixed bh->XCD map
    const int i0 = blockIdx.y * 32;
    const long base = (long)bh * kN * kDH;

    // Q B-frags (lane = query column l31, k = d)
    const u16* qg = (qtype ? qi_g : qr_g) + base;
    short8 qB0, qB1;
    {
        const u16* qp = qg + (long)(i0 + l31) * kDH;
        qB0 = *(const short8*)(qp + lh * 8);
        qB1 = *(const short8*)(qp + 16 + lh * 8);
    }

    // staging roles: per thread one b128 per {K,V} x {subtile a,b}
    const int srow = tid & 63;   // K: plane(0..1)x key31 | V: plane x d31
    const int sseg = tid >> 6;   // 8-elem segment
    const u16* kptr = ((srow < 32) ? kr_g : ki_g) + base
                    + (long)(srow & 31) * kDH + sseg * 8;
    const u16* vptr = ((srow < 32) ? vrT_g : viT_g)
                    + ((long)bh * 32 + (srow & 31)) * kN + sseg * 8;

    // K layout [bh][n][dh]: 64-key tile = 2048 elems, subtile b at +1024
    // vT layout [d][n]: 64-key tile = 64 elems along n, subtile b at +32
    short8 krA = *(const short8*)(kptr);
    short8 krB = *(const short8*)(kptr + 1024);
    short8 vrA = *(const short8*)(vptr);
    short8 vrB = *(const short8*)(vptr + 32);

    floatx16 Ur = {0}, Ui = {0};
    float La0 = 0.f, La1 = 0.f, La2 = 0.f, La3 = 0.f;

    for (int t = 0; t < 32; ++t) {
        u16* buf = (u16*)smem[t & 1];
        *(short8*)(buf + 0 * 2560 + srow * 40 + sseg * 8) = krA;
        *(short8*)(buf + 1 * 2560 + srow * 40 + sseg * 8) = krB;
        *(short8*)(buf + 2 * 2560 + srow * 40 + sseg * 8) = vrA;
        *(short8*)(buf + 3 * 2560 + srow * 40 + sseg * 8) = vrB;
        __syncthreads();
        if (t < 31) {
            krA = *(const short8*)(kptr + (long)(t + 1) * 2048);
            krB = *(const short8*)(kptr + (long)(t + 1) * 2048 + 1024);
            vrA = *(const short8*)(vptr + (t + 1) * 64);
            vrB = *(const short8*)(vptr + (t + 1) * 64 + 32);
        }
        const u16* bKa = buf;
        const u16* bKb = buf + 2560;
        const u16* bVa = buf + 5120;
        const u16* bVb = buf + 7680;

        // S for BOTH subtiles first: 4 register-independent MFMAs keep the
        // matrix pipe busy while exp_a starts on the trans pipe.
        const short8 kfA0 = *(const short8*)(bKa + (ktype * 32 + l31) * 40 + lh * 8);
        const short8 kfA1 = *(const short8*)(bKa + (ktype * 32 + l31) * 40 + 16 + lh * 8);
        const short8 kfB0 = *(const short8*)(bKb + (ktype * 32 + l31) * 40 + lh * 8);
        const short8 kfB1 = *(const short8*)(bKb + (ktype * 32 + l31) * 40 + 16 + lh * 8);
        floatx16 Sa = {0}, Sb = {0};
        Sa = MFMA_BF16(kfA0, qB0, Sa);
        Sa = MFMA_BF16(kfA1, qB1, Sa);
        Sb = MFMA_BF16(kfB0, qB0, Sb);
        Sb = MFMA_BF16(kfB1, qB1, Sb);

        // ---- subtile a: softmax (trans/VALU) then PV (matrix) ----
        float ea[16];
        #pragma unroll
        for (int r = 0; r < 16; ++r) ea[r] = __builtin_amdgcn_exp2f(Sa[r]);
        #pragma unroll
        for (int r = 0; r < 16; r += 4) {
            La0 += ea[r + 0]; La1 += ea[r + 1];
            La2 += ea[r + 2]; La3 += ea[r + 3];
        }
        const short8 FaA = mk8(&ea[0]);
        const short8 FbA = mk8(&ea[8]);
        {
            const short8 va0 = *(const short8*)(bVa + l31 * 40 + lh * 8);
            const short8 va1 = *(const short8*)(bVa + l31 * 40 + 16 + lh * 8);
            const short8 vb0 = *(const short8*)(bVa + (32 + l31) * 40 + lh * 8);
            const short8 vb1 = *(const short8*)(bVa + (32 + l31) * 40 + 16 + lh * 8);
            __builtin_amdgcn_s_setprio(1);
            Ur = MFMA_BF16(va0, FaA, Ur);
            Ur = MFMA_BF16(va1, FbA, Ur);
            Ui = MFMA_BF16(vb0, FaA, Ui);
            Ui = MFMA_BF16(vb1, FbA, Ui);
            __builtin_amdgcn_s_setprio(0);
        }

        // ---- subtile b: exp_b overlaps PV_a on the other pipe ----
        float eb[16];
        #pragma unroll
        for (int r = 0; r < 16; ++r) eb[r] = __builtin_amdgcn_exp2f(Sb[r]);
        #pragma unroll
        for (int r = 0; r < 16; r += 4) {
            La0 += eb[r + 0]; La1 += eb[r + 1];
            La2 += eb[r + 2]; La3 += eb[r + 3];
        }
        const short8 FaB = mk8(&eb[0]);
        const short8 FbB = mk8(&eb[8]);
        {
            const short8 va0 = *(const short8*)(bVb + l31 * 40 + lh * 8);
            const short8 va1 = *(const short8*)(bVb + l31 * 40 + 16 + lh * 8);
            const short8 vb0 = *(const short8*)(bVb + (32 + l31) * 40 + lh * 8);
            const short8 vb1 = *(const short8*)(bVb + (32 + l31) * 40 + 16 + lh * 8);
            __builtin_amdgcn_s_setprio(1);
            Ur = MFMA_BF16(va0, FaB, Ur);
            Ur = MFMA_BF16(va1, FbB, Ur);
            Ui = MFMA_BF16(vb0, FaB, Ui);
            Ui = MFMA_BF16(vb1, FbB, Ui);
            __builtin_amdgcn_s_setprio(0);
        }
    }

    float La = (La0 + La1) + (La2 + La3);
    La += __shfl_xor(La, 32);
    const float iL = 1.f / La;

    // per-replica signed contribution to (o_r, o_i):
    //   w0 (qr,kr): cr=+Ur, ci=+Ui
    //   w1 (qr,ki): cr=-Ui, ci=+Ur
    //   w2 (qi,kr): cr=-Ui, ci=+Ur
    //   w3 (qi,ki): cr=-Ur, ci=-Ui
    float cr[16], ci[16];
    #pragma unroll
    for (int r = 0; r < 16; ++r) {
        if (w == 0)      { cr[r] =  Ur[r] * iL; ci[r] =  Ui[r] * iL; }
        else if (w == 3) { cr[r] = -Ur[r] * iL; ci[r] = -Ui[r] * iL; }
        else             { cr[r] = -Ui[r] * iL; ci[r] =  Ur[r] * iL; }
    }

    // 3-phase replica merge in LDS (raw per-lane linear layout; all waves
    // share the same (lane,reg)->(query,d) C-mapping so reg-to-reg add is
    // exact). slot s = 2048 floats at sC + s*2048.
    __syncthreads();   // done with K/V buffers; overlay combine scratch
    float* sC = (float*)smem;
    if (qtype == 1) {                      // w2 -> slot0, w3 -> slot1
        float* dst = sC + ktype * 2048;
        #pragma unroll
        for (int r = 0; r < 16; ++r) {
            dst[r * 64 + lane] = cr[r];
            dst[1024 + r * 64 + lane] = ci[r];
        }
    }
    __syncthreads();
    if (qtype == 0) {
        float* s = sC + ktype * 2048;      // w0 reads slot0, w1 reads slot1
        #pragma unroll
        for (int r = 0; r < 16; ++r) {
            cr[r] += s[r * 64 + lane];
            ci[r] += s[1024 + r * 64 + lane];
        }
        if (ktype == 1) {                  // w1 re-dumps merged into slot1
            #pragma unroll
            for (int r = 0; r < 16; ++r) {
                s[r * 64 + lane] = cr[r];
                s[1024 + r * 64 + lane] = ci[r];
            }
        }
    }
    __syncthreads();
    if (w == 0) {
        const float* s = sC + 2048;
        #pragma unroll
        for (int r = 0; r < 16; ++r) {
            cr[r] += s[r * 64 + lane];
            ci[r] += s[1024 + r * 64 + lane];
        }
        const int b = bh >> 3, h = bh & 7;
        u16* xrow = xo + ((long)(b * 2048 + i0 + l31)) * 512 + h * 32;
        #pragma unroll
        for (int g = 0; g < 4; ++g) {
            const int d0 = 8 * g + 4 * lh;
            union { unsigned u[2]; uint2 v; } pr, pi;
            pr.u[0] = pack2(cr[4 * g + 0], cr[4 * g + 1]);
            pr.u[1] = pack2(cr[4 * g + 2], cr[4 * g + 3]);
            pi.u[0] = pack2(ci[4 * g + 0], ci[4 * g + 1]);
            pi.u[1] = pack2(ci[4 * g + 2], ci[4 * g + 3]);
            *(uint2*)(xrow + d0) = pr.v;
            *(uint2*)(xrow + 256 + d0) = pi.v;
        }
    }
}

// ---------------------------------------------------------------------------
// Output projection GEMM (unchanged).
// ---------------------------------------------------------------------------
__global__ __launch_bounds__(256, 2) void gemm_oproj(
    const u16* __restrict__ Xo, const u16* __restrict__ BT, float* __restrict__ out)
{
    __shared__ __align__(16) u16 sA[128 * 32];
    __shared__ __align__(16) u16 sB[128 * 32];
    const int tid = threadIdx.x;
    const int lane = tid & 63, l31 = lane & 31, lh = lane >> 5;
    const int w = tid >> 6, wrow = w & 1, wcol = w >> 1;
    const int srow = tid >> 2, sseg = tid & 3;
    const int n0 = blockIdx.x * 128, m0 = blockIdx.y * 128;

    floatx16 a00 = {0}, a01 = {0}, a10 = {0}, a11 = {0};

    for (int kt = 0; kt < 512; kt += 32) {
        __syncthreads();
        #pragma unroll
        for (int i = 0; i < 2; ++i) {
            const int r = srow + i * 64;
            *(short8*)(sA + r * 32 + sseg * 8) =
                *(const short8*)(Xo + (long)(m0 + r) * 512 + kt + sseg * 8);
            *(short8*)(sB + r * 32 + sseg * 8) =
                *(const short8*)(BT + (long)(n0 + r) * 512 + kt + sseg * 8);
        }
        __syncthreads();
        #pragma unroll
        for (int s = 0; s < 2; ++s) {
            const int ko = s * 16 + lh * 8;
            const short8 fa0 = *(const short8*)(sA + (wrow * 64 + l31) * 32 + ko);
            const short8 fa1 = *(const short8*)(sA + (wrow * 64 + 32 + l31) * 32 + ko);
            const short8 fb0 = *(const short8*)(sB + (wcol * 64 + l31) * 32 + ko);
            const short8 fb1 = *(const short8*)(sB + (wcol * 64 + 32 + l31) * 32 + ko);
            a00 = MFMA_BF16(fa0, fb0, a00);
            a01 = MFMA_BF16(fa0, fb1, a01);
            a10 = MFMA_BF16(fa1, fb0, a10);
            a11 = MFMA_BF16(fa1, fb1, a11);
        }
    }

    floatx16 accs[2][2] = {{a00, a01}, {a10, a11}};
    #pragma unroll
    for (int rt = 0; rt < 2; ++rt) {
        #pragma unroll
        for (int ct = 0; ct < 2; ++ct) {
            const int colb = n0 + wcol * 64 + ct * 32;
            #pragma unroll
            for (int reg = 0; reg < 16; ++reg) {
                const int row = m0 + wrow * 64 + rt * 32 + (reg & 3) + 8 * (reg >> 2) + 4 * lh;
                const int col = colb + l31;
                const float val = accs[rt][ct][reg];
                if (colb < 256) out[(long)row * 512 + col * 2] = val;
                else            out[(long)row * 512 + (col - 256) * 2 + 1] = val;
            }
        }
    }
}

extern "C" void kernel_launch(void* const* d_in, const int* in_sizes, int n_in,
                              void* d_out, int out_size, void* d_ws, size_t ws_size,
                              hipStream_t stream) {
    const float* xr    = (const float*)d_in[0];
    const float* xi    = (const float*)d_in[1];
    const float* wq_r  = (const float*)d_in[2];
    const float* wq_i  = (const float*)d_in[3];
    const float* wkv_r = (const float*)d_in[4];
    const float* wkv_i = (const float*)d_in[5];
    const float* wo_r  = (const float*)d_in[6];
    const float* wo_i  = (const float*)d_in[7];
    float* out = (float*)d_out;

    u16* ws16 = (u16*)d_ws;
    u16* qr   = ws16 + 0 * kPlane;
    u16* qi   = ws16 + 1 * kPlane;
    u16* kr   = ws16 + 2 * kPlane;
    u16* ki   = ws16 + 3 * kPlane;
    u16* vrT  = ws16 + 4 * kPlane;
    u16* viT  = ws16 + 5 * kPlane;
    u16* xo   = ws16 + 6 * kPlane;               // 2,097,152 elems
    u16* Wbig = ws16 + 8 * kPlane;               // 786,432 elems
    u16* WoT  = Wbig + 786432;                   // 262,144 elems

    prep_w<<<1024, 256, 0, stream>>>(wq_r, wq_i, wkv_r, wkv_i, wo_r, wo_i, Wbig, WoT);
    gemm_proj<<<dim3(12, 32), 256, 0, stream>>>(xr, xi, Wbig, qr, qi, kr, ki, vrT, viT);
    attn_kernel<<<dim3(kBH, kN / 32), 256, 0, stream>>>(qr, qi, kr, ki, vrT, viT, xo);
    gemm_oproj<<<dim3(4, 32), 256, 0, stream>>>(xo, WoT, out);
}

// Round 6
// 170.887 us; speedup vs baseline: 1.0820x; 1.0820x over previous
//
#include <hip/hip_runtime.h>
#include <math.h>

namespace {
constexpr int kB = 2, kN = 2048, kDim = 256, kH = 8, kDH = 32;
constexpr int kBH = kB * kH;
constexpr long kPlane = (long)kBH * kN * kDH;  // 1,048,576 elems per tensor
// DH^-0.5 / ln2 folded into stored q so softmax weight = exp2(score)
constexpr float kQScaleL2 = 0.25506852552f;
}

typedef unsigned short u16;
typedef short short8 __attribute__((ext_vector_type(8)));
typedef short short4v __attribute__((ext_vector_type(4)));
typedef float floatx16 __attribute__((ext_vector_type(16)));
#define MFMA_BF16(a, b, c) __builtin_amdgcn_mfma_f32_32x32x16_bf16(a, b, c, 0, 0, 0)

__device__ inline u16 bf16b(float x) {
    union { float f; unsigned u; } c; c.f = x;
    unsigned r = c.u + 0x7FFFu + ((c.u >> 16) & 1u);
    return (u16)(r >> 16);
}
__device__ inline unsigned pack2(float x, float y) {
    return (unsigned)bf16b(x) | ((unsigned)bf16b(y) << 16);
}
// truncating bf16 pack of two positive floats via one v_perm_b32
__device__ inline unsigned packtr(float lo, float hi) {
    return __builtin_amdgcn_perm(__float_as_uint(hi), __float_as_uint(lo), 0x07060302u);
}
__device__ inline short8 mk8(const float* e) {
    union { unsigned u[4]; short8 s; } c;
    c.u[0] = packtr(e[0], e[1]);
    c.u[1] = packtr(e[2], e[3]);
    c.u[2] = packtr(e[4], e[5]);
    c.u[3] = packtr(e[6], e[7]);
    return c.s;
}

// ---------------------------------------------------------------------------
// Build doubled/transposed bf16 weight matrices (unchanged).
// ---------------------------------------------------------------------------
__global__ __launch_bounds__(256, 2) void prep_w(
    const float* __restrict__ wq_r, const float* __restrict__ wq_i,
    const float* __restrict__ wkv_r, const float* __restrict__ wkv_i,
    const float* __restrict__ wo_r, const float* __restrict__ wo_i,
    u16* __restrict__ Wbig, u16* __restrict__ WoT)
{
    const long base = ((long)blockIdx.x * 256 + threadIdx.x) * 4;
    if (base < 786432) {
        const int c = (int)(base >> 9);
        const int k = (int)(base & 511);
        const int g = c >> 8, d = c & 255;
        const bool hi = k >= 256;
        const int k2 = hi ? k - 256 : k;
        const float* src;
        float sgn = 1.f;
        int col, stride;
        if (g < 2) {
            stride = 256; col = d;
            if (g == 0) { src = hi ? wq_i : wq_r; if (hi) sgn = -1.f; }
            else        { src = hi ? wq_r : wq_i; }
            sgn *= kQScaleL2;
        } else {
            stride = 512;
            col = (g >= 4) ? d + 256 : d;
            if ((g & 1) == 0) { src = hi ? wkv_i : wkv_r; if (hi) sgn = -1.f; }
            else              { src = hi ? wkv_r : wkv_i; }
        }
        short4v v;
        #pragma unroll
        for (int j = 0; j < 4; ++j)
            v[j] = (short)bf16b(src[(long)(k2 + j) * stride + col] * sgn);
        *(short4v*)(Wbig + base) = v;
    } else {
        const long o = base - 786432;
        const int c = (int)(o >> 9);
        const int k = (int)(o & 511);
        const bool hi = k >= 256;
        const int k2 = hi ? k - 256 : k;
        const float* src;
        float sgn = 1.f;
        int col;
        if (c < 256) { col = c;       src = hi ? wo_i : wo_r; if (hi) sgn = -1.f; }
        else         { col = c - 256; src = hi ? wo_r : wo_i; }
        short4v v;
        #pragma unroll
        for (int j = 0; j < 4; ++j)
            v[j] = (short)bf16b(src[(long)(k2 + j) * 256 + col] * sgn);
        *(short4v*)(WoT + o) = v;
    }
}

// ---------------------------------------------------------------------------
// QKV projection GEMM. vT stored [bh][32 d][2048 n] with n's bits 2<->3
// SWAPPED inside each 32-key group (PV B-frag permutation pre-applied).
// V epilogue: wave-local LDS transpose so vT stores are COALESCED (the old
// direct scatter was 2B stores at 4KB lane stride -- ~512 line transactions
// per 32x32 tile; now 32 x 64B segments per tile).
// ---------------------------------------------------------------------------
__global__ __launch_bounds__(256, 2) void gemm_proj(
    const float* __restrict__ xr_g, const float* __restrict__ xi_g,
    const u16* __restrict__ BT,
    u16* __restrict__ qr, u16* __restrict__ qi, u16* __restrict__ kr,
    u16* __restrict__ ki, u16* __restrict__ vrT, u16* __restrict__ viT)
{
    __shared__ __align__(16) u16 sAB[8192];   // sA | sB ; epilogue scratch overlay
    u16* sA = sAB;
    u16* sB = sAB + 4096;
    const int tid = threadIdx.x;
    const int lane = tid & 63, l31 = lane & 31, lh = lane >> 5;
    const int w = tid >> 6, wrow = w & 1, wcol = w >> 1;
    const int srow = tid >> 2, sseg = tid & 3;
    const int n0 = blockIdx.x * 128, m0 = blockIdx.y * 128;

    floatx16 a00 = {0}, a01 = {0}, a10 = {0}, a11 = {0};

    for (int kt = 0; kt < 512; kt += 32) {
        __syncthreads();
        const float* xbase = (kt < 256) ? xr_g : xi_g;
        const int kc = (kt & 255) + sseg * 8;
        #pragma unroll
        for (int i = 0; i < 2; ++i) {
            const int r = srow + i * 64;
            {
                const float* src = xbase + (long)(m0 + r) * 256 + kc;
                const float4 f0 = *(const float4*)(src);
                const float4 f1 = *(const float4*)(src + 4);
                short8 v;
                v[0] = (short)bf16b(f0.x); v[1] = (short)bf16b(f0.y);
                v[2] = (short)bf16b(f0.z); v[3] = (short)bf16b(f0.w);
                v[4] = (short)bf16b(f1.x); v[5] = (short)bf16b(f1.y);
                v[6] = (short)bf16b(f1.z); v[7] = (short)bf16b(f1.w);
                *(short8*)(sA + r * 32 + sseg * 8) = v;
            }
            *(short8*)(sB + r * 32 + sseg * 8) =
                *(const short8*)(BT + (long)(n0 + r) * 512 + kt + sseg * 8);
        }
        __syncthreads();
        #pragma unroll
        for (int s = 0; s < 2; ++s) {
            const int ko = s * 16 + lh * 8;
            const short8 fa0 = *(const short8*)(sA + (wrow * 64 + l31) * 32 + ko);
            const short8 fa1 = *(const short8*)(sA + (wrow * 64 + 32 + l31) * 32 + ko);
            const short8 fb0 = *(const short8*)(sB + (wcol * 64 + l31) * 32 + ko);
            const short8 fb1 = *(const short8*)(sB + (wcol * 64 + 32 + l31) * 32 + ko);
            a00 = MFMA_BF16(fa0, fb0, a00);
            a01 = MFMA_BF16(fa0, fb1, a01);
            a10 = MFMA_BF16(fa1, fb0, a10);
            a11 = MFMA_BF16(fa1, fb1, a11);
        }
    }

    __syncthreads();   // k-loop tiles fully consumed; sAB becomes scratch
    // per-wave transpose scratch: 32 rows (d) x 34 pitch u16 = 2176 B
    u16* scr = sAB + w * 1088;

    floatx16 accs[2][2] = {{a00, a01}, {a10, a11}};
    #pragma unroll
    for (int rt = 0; rt < 2; ++rt) {
        #pragma unroll
        for (int ct = 0; ct < 2; ++ct) {
            const int colb = n0 + wcol * 64 + ct * 32;
            const int g = colb >> 8;
            const int h = (colb & 255) >> 5;
            if (g < 4) {
                u16* pl = (g == 0) ? qr : (g == 1) ? qi : (g == 2) ? kr : ki;
                #pragma unroll
                for (int reg = 0; reg < 16; ++reg) {
                    const int row = m0 + wrow * 64 + rt * 32 + (reg & 3) + 8 * (reg >> 2) + 4 * lh;
                    const int b = row >> 11, nn = row & 2047;
                    pl[(((long)(b * 8 + h)) * 2048 + nn) * 32 + l31] = bf16b(accs[rt][ct][reg]);
                }
            } else {
                // ---- coalesced vT store via wave-local LDS transpose ----
                // step A: scratch[d = l31][r] <- C[r][d], r = 8q + 4lh + 0..3
                #pragma unroll
                for (int q = 0; q < 4; ++q) {
                    union { unsigned u[2]; uint2 v; } pk;
                    pk.u[0] = pack2(accs[rt][ct][4 * q + 0], accs[rt][ct][4 * q + 1]);
                    pk.u[1] = pack2(accs[rt][ct][4 * q + 2], accs[rt][ct][4 * q + 3]);
                    *(uint2*)(scr + l31 * 34 + 8 * q + 4 * lh) = pk.v;
                }
                asm volatile("s_waitcnt lgkmcnt(0)" ::: "memory");
                // step B: lane (p = lane&15, dgrp = lane>>4) stores the n-pair
                // (2p, 2p+1) of rows d = ds*4 + dgrp. np permutation (swap n
                // bits 2<->3) = swap p bits 1<->2 on the pair index, applied
                // on the scratch READ so stores stay contiguous.
                const int rowb = m0 + wrow * 64 + rt * 32;
                const int b_ = rowb >> 11, nnb = rowb & 2047;
                u16* plane = (g == 4) ? vrT : viT;
                u16* rowbase = plane + ((long)(b_ * 8 + h) * 32) * 2048 + nnb;
                const int p = lane & 15;
                const int sp = (p & ~6) | ((p & 2) << 1) | ((p & 4) >> 1);
                const int dgrp = lane >> 4;
                #pragma unroll
                for (int ds_ = 0; ds_ < 8; ++ds_) {
                    const int d = ds_ * 4 + dgrp;
                    const unsigned v = *(const unsigned*)(scr + d * 34 + 2 * sp);
                    *(unsigned*)(rowbase + (long)d * 2048 + 2 * p) = v;
                }
                asm volatile("s_waitcnt lgkmcnt(0)" ::: "memory");  // scratch reuse (WAR)
            }
        }
    }
}

// ---------------------------------------------------------------------------
// MFMA flash attention (R0 version, 63.4 us measured -- proven best).
// S^T = K.Q^T (C-layout: lane = query col, regs = key rows).
// PV B-frags are 4 v_perm packs of the lane's OWN exp regs; the required
// key permutation (bits 2<->3 of n) is pre-applied to V's global layout.
// Double-buffered K/V staging, 1 barrier per 32-key tile, 2 blocks/CU.
// ---------------------------------------------------------------------------
__global__ __launch_bounds__(256, 2) void attn_kernel(
    const u16* __restrict__ qr_g, const u16* __restrict__ qi_g,
    const u16* __restrict__ kr_g, const u16* __restrict__ ki_g,
    const u16* __restrict__ vrT_g, const u16* __restrict__ viT_g,
    u16* __restrict__ xo)
{
    __shared__ __align__(16) u16 smem[2][2][64 * 40];   // [K/V][buf] 20.0 KiB

    const int tid = threadIdx.x;
    const int lane = tid & 63, l31 = lane & 31, lh = lane >> 5;
    const int w = tid >> 6, strip = w & 1, qtype = w >> 1;
    const int bh = blockIdx.x;          // bh-major: per-XCD L2 locality
    const int i0 = blockIdx.y * 64;
    const long base = (long)bh * kN * kDH;

    // Q B-frags (lane = query column l31, k = d)
    const u16* qg = (qtype ? qi_g : qr_g) + base;
    short8 qB0, qB1;
    {
        const u16* qp = qg + (long)(i0 + strip * 32 + l31) * kDH;
        qB0 = *(const short8*)(qp + lh * 8);
        qB1 = *(const short8*)(qp + 16 + lh * 8);
    }

    // staging roles: one b128 per thread for K and V
    const int srow = tid & 63;   // K: bigkey row | V: vcol row
    const int sseg = tid >> 6;   // 8-elem segment
    const u16* kptr = ((srow < 32) ? kr_g : ki_g) + base
                    + (long)(srow & 31) * kDH + sseg * 8;
    const u16* vptr = ((srow < 32) ? vrT_g : viT_g)
                    + ((long)bh * 32 + (srow & 31)) * kN + sseg * 8;

    short8 kreg = *(const short8*)kptr;
    short8 vreg = *(const short8*)vptr;

    floatx16 U0r = {0}, U0i = {0}, U1r = {0}, U1i = {0};
    float La0 = 0.f, La1 = 0.f;

    for (int t = 0; t < 64; ++t) {
        u16* bK = smem[0][t & 1];
        u16* bV = smem[1][t & 1];
        *(short8*)(bK + srow * 40 + sseg * 8) = kreg;
        *(short8*)(bV + srow * 40 + sseg * 8) = vreg;
        __syncthreads();
        if (t < 63) {
            // K layout [bh][n][dh]: one 32-key tile = 1024 elems
            kreg = *(const short8*)(kptr + (long)(t + 1) * 1024);
            // vT layout [d][n]: one 32-key tile = 32 elems along n
            vreg = *(const short8*)(vptr + (t + 1) * 32);
        }

        // S^T: A = K rows (kr: 0..31, ki: 32..63), B = Q
        const short8 ka0 = *(const short8*)(bK + l31 * 40 + lh * 8);
        const short8 ka1 = *(const short8*)(bK + l31 * 40 + 16 + lh * 8);
        const short8 kb0 = *(const short8*)(bK + (32 + l31) * 40 + lh * 8);
        const short8 kb1 = *(const short8*)(bK + (32 + l31) * 40 + 16 + lh * 8);
        floatx16 S0 = {0}, S1 = {0};
        S0 = MFMA_BF16(ka0, qB0, S0);
        S0 = MFMA_BF16(ka1, qB1, S0);
        S1 = MFMA_BF16(kb0, qB0, S1);
        S1 = MFMA_BF16(kb1, qB1, S1);

        float e0[16], e1[16];
        #pragma unroll
        for (int r = 0; r < 16; ++r) {
            e0[r] = __builtin_amdgcn_exp2f(S0[r]);
            La0 += e0[r];
        }
        #pragma unroll
        for (int r = 0; r < 16; ++r) {
            e1[r] = __builtin_amdgcn_exp2f(S1[r]);
            La1 += e1[r];
        }
        // PV B-frags from own regs (permutation pre-applied in V layout)
        const short8 F0a = mk8(&e0[0]);
        const short8 F0b = mk8(&e0[8]);
        const short8 F1a = mk8(&e1[0]);
        const short8 F1b = mk8(&e1[8]);

        // V^T A-frags (vr rows 0..31, vi rows 32..63)
        const short8 va0 = *(const short8*)(bV + l31 * 40 + lh * 8);
        const short8 va1 = *(const short8*)(bV + l31 * 40 + 16 + lh * 8);
        const short8 vb0 = *(const short8*)(bV + (32 + l31) * 40 + lh * 8);
        const short8 vb1 = *(const short8*)(bV + (32 + l31) * 40 + 16 + lh * 8);

        U0r = MFMA_BF16(va0, F0a, U0r);
        U0r = MFMA_BF16(va1, F0b, U0r);
        U0i = MFMA_BF16(vb0, F0a, U0i);
        U0i = MFMA_BF16(vb1, F0b, U0i);
        U1r = MFMA_BF16(va0, F1a, U1r);
        U1r = MFMA_BF16(va1, F1b, U1r);
        U1i = MFMA_BF16(vb0, F1a, U1i);
        U1i = MFMA_BF16(vb1, F1b, U1i);
    }

    La0 += __shfl_xor(La0, 32);
    La1 += __shfl_xor(La1, 32);
    const float iL0 = 1.f / La0, iL1 = 1.f / La1;

    float po_r[16], po_i[16];
    #pragma unroll
    for (int r = 0; r < 16; ++r) {
        if (qtype == 0) {
            po_r[r] =  U0r[r] * iL0 - U1i[r] * iL1;
            po_i[r] =  U0i[r] * iL0 + U1r[r] * iL1;
        } else {
            po_r[r] = -U0i[r] * iL0 - U1r[r] * iL1;
            po_i[r] =  U0r[r] * iL0 - U1i[r] * iL1;
        }
    }

    __syncthreads();   // done with K/V buffers; overlay combine scratch
    float* sC = (float*)smem;   // [strip][2][32 d][33]
    if (qtype == 1) {
        float* dst = sC + strip * (2 * 32 * 33);
        #pragma unroll
        for (int r = 0; r < 16; ++r) {
            const int d = (r & 3) + 8 * (r >> 2) + 4 * lh;
            dst[d * 33 + l31] = po_r[r];
            dst[32 * 33 + d * 33 + l31] = po_i[r];
        }
    }
    __syncthreads();
    if (qtype == 0) {
        const float* src = sC + strip * (2 * 32 * 33);
        const int b = bh >> 3, h = bh & 7;
        u16* xrow = xo + ((long)(b * 2048 + i0 + strip * 32 + l31)) * 512 + h * 32;
        #pragma unroll
        for (int g = 0; g < 4; ++g) {
            const int d0 = 8 * g + 4 * lh;
            union { unsigned u[2]; uint2 v; } pr, pi;
            pr.u[0] = pack2(po_r[4 * g + 0] + src[(d0 + 0) * 33 + l31],
                            po_r[4 * g + 1] + src[(d0 + 1) * 33 + l31]);
            pr.u[1] = pack2(po_r[4 * g + 2] + src[(d0 + 2) * 33 + l31],
                            po_r[4 * g + 3] + src[(d0 + 3) * 33 + l31]);
            pi.u[0] = pack2(po_i[4 * g + 0] + src[32 * 33 + (d0 + 0) * 33 + l31],
                            po_i[4 * g + 1] + src[32 * 33 + (d0 + 1) * 33 + l31]);
            pi.u[1] = pack2(po_i[4 * g + 2] + src[32 * 33 + (d0 + 2) * 33 + l31],
                            po_i[4 * g + 3] + src[32 * 33 + (d0 + 3) * 33 + l31]);
            *(uint2*)(xrow + d0) = pr.v;
            *(uint2*)(xrow + 256 + d0) = pi.v;
        }
    }
}

// ---------------------------------------------------------------------------
// Output projection GEMM (unchanged).
// ---------------------------------------------------------------------------
__global__ __launch_bounds__(256, 2) void gemm_oproj(
    const u16* __restrict__ Xo, const u16* __restrict__ BT, float* __restrict__ out)
{
    __shared__ __align__(16) u16 sA[128 * 32];
    __shared__ __align__(16) u16 sB[128 * 32];
    const int tid = threadIdx.x;
    const int lane = tid & 63, l31 = lane & 31, lh = lane >> 5;
    const int w = tid >> 6, wrow = w & 1, wcol = w >> 1;
    const int srow = tid >> 2, sseg = tid & 3;
    const int n0 = blockIdx.x * 128, m0 = blockIdx.y * 128;

    floatx16 a00 = {0}, a01 = {0}, a10 = {0}, a11 = {0};

    for (int kt = 0; kt < 512; kt += 32) {
        __syncthreads();
        #pragma unroll
        for (int i = 0; i < 2; ++i) {
            const int r = srow + i * 64;
            *(short8*)(sA + r * 32 + sseg * 8) =
                *(const short8*)(Xo + (long)(m0 + r) * 512 + kt + sseg * 8);
            *(short8*)(sB + r * 32 + sseg * 8) =
                *(const short8*)(BT + (long)(n0 + r) * 512 + kt + sseg * 8);
        }
        __syncthreads();
        #pragma unroll
        for (int s = 0; s < 2; ++s) {
            const int ko = s * 16 + lh * 8;
            const short8 fa0 = *(const short8*)(sA + (wrow * 64 + l31) * 32 + ko);
            const short8 fa1 = *(const short8*)(sA + (wrow * 64 + 32 + l31) * 32 + ko);
            const short8 fb0 = *(const short8*)(sB + (wcol * 64 + l31) * 32 + ko);
            const short8 fb1 = *(const short8*)(sB + (wcol * 64 + 32 + l31) * 32 + ko);
            a00 = MFMA_BF16(fa0, fb0, a00);
            a01 = MFMA_BF16(fa0, fb1, a01);
            a10 = MFMA_BF16(fa1, fb0, a10);
            a11 = MFMA_BF16(fa1, fb1, a11);
        }
    }

    floatx16 accs[2][2] = {{a00, a01}, {a10, a11}};
    #pragma unroll
    for (int rt = 0; rt < 2; ++rt) {
        #pragma unroll
        for (int ct = 0; ct < 2; ++ct) {
            const int colb = n0 + wcol * 64 + ct * 32;
            #pragma unroll
            for (int reg = 0; reg < 16; ++reg) {
                const int row = m0 + wrow * 64 + rt * 32 + (reg & 3) + 8 * (reg >> 2) + 4 * lh;
                const int col = colb + l31;
                const float val = accs[rt][ct][reg];
                if (colb < 256) out[(long)row * 512 + col * 2] = val;
                else            out[(long)row * 512 + (col - 256) * 2 + 1] = val;
            }
        }
    }
}

extern "C" void kernel_launch(void* const* d_in, const int* in_sizes, int n_in,
                              void* d_out, int out_size, void* d_ws, size_t ws_size,
                              hipStream_t stream) {
    const float* xr    = (const float*)d_in[0];
    const float* xi    = (const float*)d_in[1];
    const float* wq_r  = (const float*)d_in[2];
    const float* wq_i  = (const float*)d_in[3];
    const float* wkv_r = (const float*)d_in[4];
    const float* wkv_i = (const float*)d_in[5];
    const float* wo_r  = (const float*)d_in[6];
    const float* wo_i  = (const float*)d_in[7];
    float* out = (float*)d_out;

    u16* ws16 = (u16*)d_ws;
    u16* qr   = ws16 + 0 * kPlane;
    u16* qi   = ws16 + 1 * kPlane;
    u16* kr   = ws16 + 2 * kPlane;
    u16* ki   = ws16 + 3 * kPlane;
    u16* vrT  = ws16 + 4 * kPlane;
    u16* viT  = ws16 + 5 * kPlane;
    u16* xo   = ws16 + 6 * kPlane;               // 2,097,152 elems
    u16* Wbig = ws16 + 8 * kPlane;               // 786,432 elems
    u16* WoT  = Wbig + 786432;                   // 262,144 elems

    prep_w<<<1024, 256, 0, stream>>>(wq_r, wq_i, wkv_r, wkv_i, wo_r, wo_i, Wbig, WoT);
    gemm_proj<<<dim3(12, 32), 256, 0, stream>>>(xr, xi, Wbig, qr, qi, kr, ki, vrT, viT);
    attn_kernel<<<dim3(kBH, kN / 64), 256, 0, stream>>>(qr, qi, kr, ki, vrT, viT, xo);
    gemm_oproj<<<dim3(4, 32), 256, 0, stream>>>(xo, WoT, out);
}

// Round 7
// 168.004 us; speedup vs baseline: 1.1006x; 1.0172x over previous
//
#include <hip/hip_runtime.h>
#include <math.h>

namespace {
constexpr int kB = 2, kN = 2048, kDim = 256, kH = 8, kDH = 32;
constexpr int kBH = kB * kH;
constexpr long kPlane = (long)kBH * kN * kDH;  // 1,048,576 elems per tensor
// DH^-0.5 / ln2 folded into stored q so softmax weight = exp2(score)
constexpr float kQScaleL2 = 0.25506852552f;
}

typedef unsigned short u16;
typedef short short8 __attribute__((ext_vector_type(8)));
typedef short short4v __attribute__((ext_vector_type(4)));
typedef float floatx16 __attribute__((ext_vector_type(16)));
#define MFMA_BF16(a, b, c) __builtin_amdgcn_mfma_f32_32x32x16_bf16(a, b, c, 0, 0, 0)

__device__ inline u16 bf16b(float x) {
    union { float f; unsigned u; } c; c.f = x;
    unsigned r = c.u + 0x7FFFu + ((c.u >> 16) & 1u);
    return (u16)(r >> 16);
}
__device__ inline unsigned pack2(float x, float y) {
    return (unsigned)bf16b(x) | ((unsigned)bf16b(y) << 16);
}
// truncating bf16 pack of two positive floats via one v_perm_b32
__device__ inline unsigned packtr(float lo, float hi) {
    return __builtin_amdgcn_perm(__float_as_uint(hi), __float_as_uint(lo), 0x07060302u);
}
__device__ inline short8 mk8(const float* e) {
    union { unsigned u[4]; short8 s; } c;
    c.u[0] = packtr(e[0], e[1]);
    c.u[1] = packtr(e[2], e[3]);
    c.u[2] = packtr(e[4], e[5]);
    c.u[3] = packtr(e[6], e[7]);
    return c.s;
}
// async global->LDS: 16B per lane, LDS dest = wave-uniform base + lane*16
__device__ inline void gload16(const u16* g, u16* l) {
    __builtin_amdgcn_global_load_lds(
        (const __attribute__((address_space(1))) void*)g,
        (__attribute__((address_space(3))) void*)l, 16, 0, 0);
}

// ---------------------------------------------------------------------------
// prep: doubled/transposed bf16 weights + x f32->bf16 conversion.
// Xbf[row][512]: cols 0..255 = xr, 256..511 = xi (matches Wbig K layout).
// WoT columns INTERLEAVED (d,ri): row c = weight col d=c>>1, ri=c&1 -> the
// oproj epilogue stores consecutive f32 (out flat idx = row*512 + c).
// ---------------------------------------------------------------------------
__global__ __launch_bounds__(256, 2) void prep_w(
    const float* __restrict__ xr_g, const float* __restrict__ xi_g,
    const float* __restrict__ wq_r, const float* __restrict__ wq_i,
    const float* __restrict__ wkv_r, const float* __restrict__ wkv_i,
    const float* __restrict__ wo_r, const float* __restrict__ wo_i,
    u16* __restrict__ Wbig, u16* __restrict__ WoT, u16* __restrict__ Xbf)
{
    const long base = ((long)blockIdx.x * 256 + threadIdx.x) * 4;
    if (base < 786432) {
        const int c = (int)(base >> 9);
        const int k = (int)(base & 511);
        const int g = c >> 8, d = c & 255;
        const bool hi = k >= 256;
        const int k2 = hi ? k - 256 : k;
        const float* src;
        float sgn = 1.f;
        int col, stride;
        if (g < 2) {
            stride = 256; col = d;
            if (g == 0) { src = hi ? wq_i : wq_r; if (hi) sgn = -1.f; }
            else        { src = hi ? wq_r : wq_i; }
            sgn *= kQScaleL2;
        } else {
            stride = 512;
            col = (g >= 4) ? d + 256 : d;
            if ((g & 1) == 0) { src = hi ? wkv_i : wkv_r; if (hi) sgn = -1.f; }
            else              { src = hi ? wkv_r : wkv_i; }
        }
        short4v v;
        #pragma unroll
        for (int j = 0; j < 4; ++j)
            v[j] = (short)bf16b(src[(long)(k2 + j) * stride + col] * sgn);
        *(short4v*)(Wbig + base) = v;
    } else if (base < 1048576) {
        const long o = base - 786432;
        const int c = (int)(o >> 9);          // interleaved output col
        const int k = (int)(o & 511);
        const bool hi = k >= 256;
        const int k2 = hi ? k - 256 : k;
        const int col = c >> 1;               // weight column d
        const float* src;
        float sgn = 1.f;
        if ((c & 1) == 0) { src = hi ? wo_i : wo_r; if (hi) sgn = -1.f; }
        else              { src = hi ? wo_r : wo_i; }
        short4v v;
        #pragma unroll
        for (int j = 0; j < 4; ++j)
            v[j] = (short)bf16b(src[(long)(k2 + j) * 256 + col] * sgn);
        *(short4v*)(WoT + o) = v;
    } else {
        const long o = base - 1048576;        // 0 .. 2097151
        const int row = (int)(o >> 9);
        const int col = (int)(o & 511);
        const float* src = (col < 256) ? (xr_g + (long)row * 256 + col)
                                       : (xi_g + (long)row * 256 + col - 256);
        const float4 f = *(const float4*)src;
        short4v v;
        v[0] = (short)bf16b(f.x); v[1] = (short)bf16b(f.y);
        v[2] = (short)bf16b(f.z); v[3] = (short)bf16b(f.w);
        *(short4v*)(Xbf + o) = v;
    }
}

// ---------------------------------------------------------------------------
// QKV projection GEMM v2: A from pre-converted Xbf, both tiles staged via
// global_load_lds (16B/lane), double-buffered, ONE barrier per k-tile (the
// drain of tile t's loads is covered by tile t-1's compute). No conversion
// VALU in the hot loop. Epilogue (incl. V LDS-transpose store) unchanged.
// ---------------------------------------------------------------------------
__global__ __launch_bounds__(256, 2) void gemm_proj(
    const u16* __restrict__ Xbf, const u16* __restrict__ BT,
    u16* __restrict__ qr, u16* __restrict__ qi, u16* __restrict__ kr,
    u16* __restrict__ ki, u16* __restrict__ vrT, u16* __restrict__ viT)
{
    __shared__ __align__(16) u16 sA[2][128 * 32];
    __shared__ __align__(16) u16 sB[2][128 * 32];
    const int tid = threadIdx.x;
    const int lane = tid & 63, l31 = lane & 31, lh = lane >> 5;
    const int w = tid >> 6, wrow = w & 1, wcol = w >> 1;
    const int n0 = blockIdx.x * 128, m0 = blockIdx.y * 128;

    // staging roles: wave w owns rows [32w, 32w+32); lane -> row 32w+16h+(l>>2), seg l&3
    const int rb0 = w * 32;
    const int grow = lane >> 2;
    const int gseg = (lane & 3) * 8;

    auto stage = [&](int b, int kt) {
        #pragma unroll
        for (int half = 0; half < 2; ++half) {
            const int r = rb0 + half * 16;
            gload16(Xbf + (long)(m0 + r + grow) * 512 + kt + gseg, &sA[b][r * 32]);
            gload16(BT + (long)(n0 + r + grow) * 512 + kt + gseg, &sB[b][r * 32]);
        }
    };

    floatx16 a00 = {0}, a01 = {0}, a10 = {0}, a11 = {0};
    stage(0, 0);
    for (int it = 0; it < 16; ++it) {
        const int cur = it & 1;
        __syncthreads();                      // drains vmcnt: buf[cur] ready
        if (it < 15) stage(cur ^ 1, (it + 1) * 32);
        #pragma unroll
        for (int s = 0; s < 2; ++s) {
            const int ko = s * 16 + lh * 8;
            const short8 fa0 = *(const short8*)(&sA[cur][(wrow * 64 + l31) * 32 + ko]);
            const short8 fa1 = *(const short8*)(&sA[cur][(wrow * 64 + 32 + l31) * 32 + ko]);
            const short8 fb0 = *(const short8*)(&sB[cur][(wcol * 64 + l31) * 32 + ko]);
            const short8 fb1 = *(const short8*)(&sB[cur][(wcol * 64 + 32 + l31) * 32 + ko]);
            a00 = MFMA_BF16(fa0, fb0, a00);
            a01 = MFMA_BF16(fa0, fb1, a01);
            a10 = MFMA_BF16(fa1, fb0, a10);
            a11 = MFMA_BF16(fa1, fb1, a11);
        }
    }

    __syncthreads();   // tiles fully consumed; LDS becomes scratch
    // per-wave transpose scratch: 32 rows (d) x 34 pitch u16 = 2176 B
    u16* scr = ((u16*)sA) + w * 1088;

    floatx16 accs[2][2] = {{a00, a01}, {a10, a11}};
    #pragma unroll
    for (int rt = 0; rt < 2; ++rt) {
        #pragma unroll
        for (int ct = 0; ct < 2; ++ct) {
            const int colb = n0 + wcol * 64 + ct * 32;
            const int g = colb >> 8;
            const int h = (colb & 255) >> 5;
            if (g < 4) {
                u16* pl = (g == 0) ? qr : (g == 1) ? qi : (g == 2) ? kr : ki;
                #pragma unroll
                for (int reg = 0; reg < 16; ++reg) {
                    const int row = m0 + wrow * 64 + rt * 32 + (reg & 3) + 8 * (reg >> 2) + 4 * lh;
                    const int b = row >> 11, nn = row & 2047;
                    pl[(((long)(b * 8 + h)) * 2048 + nn) * 32 + l31] = bf16b(accs[rt][ct][reg]);
                }
            } else {
                // ---- coalesced vT store via wave-local LDS transpose ----
                #pragma unroll
                for (int q = 0; q < 4; ++q) {
                    union { unsigned u[2]; uint2 v; } pk;
                    pk.u[0] = pack2(accs[rt][ct][4 * q + 0], accs[rt][ct][4 * q + 1]);
                    pk.u[1] = pack2(accs[rt][ct][4 * q + 2], accs[rt][ct][4 * q + 3]);
                    *(uint2*)(scr + l31 * 34 + 8 * q + 4 * lh) = pk.v;
                }
                asm volatile("s_waitcnt lgkmcnt(0)" ::: "memory");
                const int rowb = m0 + wrow * 64 + rt * 32;
                const int b_ = rowb >> 11, nnb = rowb & 2047;
                u16* plane = (g == 4) ? vrT : viT;
                u16* rowbase = plane + ((long)(b_ * 8 + h) * 32) * 2048 + nnb;
                const int p = lane & 15;
                const int sp = (p & ~6) | ((p & 2) << 1) | ((p & 4) >> 1);
                const int dgrp = lane >> 4;
                #pragma unroll
                for (int ds_ = 0; ds_ < 8; ++ds_) {
                    const int d = ds_ * 4 + dgrp;
                    const unsigned v = *(const unsigned*)(scr + d * 34 + 2 * sp);
                    *(unsigned*)(rowbase + (long)d * 2048 + 2 * p) = v;
                }
                asm volatile("s_waitcnt lgkmcnt(0)" ::: "memory");  // scratch WAR
            }
        }
    }
}

// ---------------------------------------------------------------------------
// MFMA flash attention (R0/R6 version, 62.0 us measured -- proven best).
// ---------------------------------------------------------------------------
__global__ __launch_bounds__(256, 2) void attn_kernel(
    const u16* __restrict__ qr_g, const u16* __restrict__ qi_g,
    const u16* __restrict__ kr_g, const u16* __restrict__ ki_g,
    const u16* __restrict__ vrT_g, const u16* __restrict__ viT_g,
    u16* __restrict__ xo)
{
    __shared__ __align__(16) u16 smem[2][2][64 * 40];   // [K/V][buf] 20.0 KiB

    const int tid = threadIdx.x;
    const int lane = tid & 63, l31 = lane & 31, lh = lane >> 5;
    const int w = tid >> 6, strip = w & 1, qtype = w >> 1;
    const int bh = blockIdx.x;          // bh-major: per-XCD L2 locality
    const int i0 = blockIdx.y * 64;
    const long base = (long)bh * kN * kDH;

    // Q B-frags (lane = query column l31, k = d)
    const u16* qg = (qtype ? qi_g : qr_g) + base;
    short8 qB0, qB1;
    {
        const u16* qp = qg + (long)(i0 + strip * 32 + l31) * kDH;
        qB0 = *(const short8*)(qp + lh * 8);
        qB1 = *(const short8*)(qp + 16 + lh * 8);
    }

    // staging roles: one b128 per thread for K and V
    const int srow = tid & 63;   // K: bigkey row | V: vcol row
    const int sseg = tid >> 6;   // 8-elem segment
    const u16* kptr = ((srow < 32) ? kr_g : ki_g) + base
                    + (long)(srow & 31) * kDH + sseg * 8;
    const u16* vptr = ((srow < 32) ? vrT_g : viT_g)
                    + ((long)bh * 32 + (srow & 31)) * kN + sseg * 8;

    short8 kreg = *(const short8*)kptr;
    short8 vreg = *(const short8*)vptr;

    floatx16 U0r = {0}, U0i = {0}, U1r = {0}, U1i = {0};
    float La0 = 0.f, La1 = 0.f;

    for (int t = 0; t < 64; ++t) {
        u16* bK = smem[0][t & 1];
        u16* bV = smem[1][t & 1];
        *(short8*)(bK + srow * 40 + sseg * 8) = kreg;
        *(short8*)(bV + srow * 40 + sseg * 8) = vreg;
        __syncthreads();
        if (t < 63) {
            kreg = *(const short8*)(kptr + (long)(t + 1) * 1024);
            vreg = *(const short8*)(vptr + (t + 1) * 32);
        }

        // S^T: A = K rows (kr: 0..31, ki: 32..63), B = Q
        const short8 ka0 = *(const short8*)(bK + l31 * 40 + lh * 8);
        const short8 ka1 = *(const short8*)(bK + l31 * 40 + 16 + lh * 8);
        const short8 kb0 = *(const short8*)(bK + (32 + l31) * 40 + lh * 8);
        const short8 kb1 = *(const short8*)(bK + (32 + l31) * 40 + 16 + lh * 8);
        floatx16 S0 = {0}, S1 = {0};
        S0 = MFMA_BF16(ka0, qB0, S0);
        S0 = MFMA_BF16(ka1, qB1, S0);
        S1 = MFMA_BF16(kb0, qB0, S1);
        S1 = MFMA_BF16(kb1, qB1, S1);

        float e0[16], e1[16];
        #pragma unroll
        for (int r = 0; r < 16; ++r) {
            e0[r] = __builtin_amdgcn_exp2f(S0[r]);
            La0 += e0[r];
        }
        #pragma unroll
        for (int r = 0; r < 16; ++r) {
            e1[r] = __builtin_amdgcn_exp2f(S1[r]);
            La1 += e1[r];
        }
        const short8 F0a = mk8(&e0[0]);
        const short8 F0b = mk8(&e0[8]);
        const short8 F1a = mk8(&e1[0]);
        const short8 F1b = mk8(&e1[8]);

        const short8 va0 = *(const short8*)(bV + l31 * 40 + lh * 8);
        const short8 va1 = *(const short8*)(bV + l31 * 40 + 16 + lh * 8);
        const short8 vb0 = *(const short8*)(bV + (32 + l31) * 40 + lh * 8);
        const short8 vb1 = *(const short8*)(bV + (32 + l31) * 40 + 16 + lh * 8);

        U0r = MFMA_BF16(va0, F0a, U0r);
        U0r = MFMA_BF16(va1, F0b, U0r);
        U0i = MFMA_BF16(vb0, F0a, U0i);
        U0i = MFMA_BF16(vb1, F0b, U0i);
        U1r = MFMA_BF16(va0, F1a, U1r);
        U1r = MFMA_BF16(va1, F1b, U1r);
        U1i = MFMA_BF16(vb0, F1a, U1i);
        U1i = MFMA_BF16(vb1, F1b, U1i);
    }

    La0 += __shfl_xor(La0, 32);
    La1 += __shfl_xor(La1, 32);
    const float iL0 = 1.f / La0, iL1 = 1.f / La1;

    float po_r[16], po_i[16];
    #pragma unroll
    for (int r = 0; r < 16; ++r) {
        if (qtype == 0) {
            po_r[r] =  U0r[r] * iL0 - U1i[r] * iL1;
            po_i[r] =  U0i[r] * iL0 + U1r[r] * iL1;
        } else {
            po_r[r] = -U0i[r] * iL0 - U1r[r] * iL1;
            po_i[r] =  U0r[r] * iL0 - U1i[r] * iL1;
        }
    }

    __syncthreads();   // done with K/V buffers; overlay combine scratch
    float* sC = (float*)smem;   // [strip][2][32 d][33]
    if (qtype == 1) {
        float* dst = sC + strip * (2 * 32 * 33);
        #pragma unroll
        for (int r = 0; r < 16; ++r) {
            const int d = (r & 3) + 8 * (r >> 2) + 4 * lh;
            dst[d * 33 + l31] = po_r[r];
            dst[32 * 33 + d * 33 + l31] = po_i[r];
        }
    }
    __syncthreads();
    if (qtype == 0) {
        const float* src = sC + strip * (2 * 32 * 33);
        const int b = bh >> 3, h = bh & 7;
        u16* xrow = xo + ((long)(b * 2048 + i0 + strip * 32 + l31)) * 512 + h * 32;
        #pragma unroll
        for (int g = 0; g < 4; ++g) {
            const int d0 = 8 * g + 4 * lh;
            union { unsigned u[2]; uint2 v; } pr, pi;
            pr.u[0] = pack2(po_r[4 * g + 0] + src[(d0 + 0) * 33 + l31],
                            po_r[4 * g + 1] + src[(d0 + 1) * 33 + l31]);
            pr.u[1] = pack2(po_r[4 * g + 2] + src[(d0 + 2) * 33 + l31],
                            po_r[4 * g + 3] + src[(d0 + 3) * 33 + l31]);
            pi.u[0] = pack2(po_i[4 * g + 0] + src[32 * 33 + (d0 + 0) * 33 + l31],
                            po_i[4 * g + 1] + src[32 * 33 + (d0 + 1) * 33 + l31]);
            pi.u[1] = pack2(po_i[4 * g + 2] + src[32 * 33 + (d0 + 2) * 33 + l31],
                            po_i[4 * g + 3] + src[32 * 33 + (d0 + 3) * 33 + l31]);
            *(uint2*)(xrow + d0) = pr.v;
            *(uint2*)(xrow + 256 + d0) = pi.v;
        }
    }
}

// ---------------------------------------------------------------------------
// Output projection GEMM v2: 64x64 tiles -> 512 blocks (2 waves/SIMD, was
// 0.5), global_load_lds double-buffered 1-barrier k-loop, and WoT column
// interleave makes the f32 stores fully coalesced (out idx = row*512 + col).
// ---------------------------------------------------------------------------
__global__ __launch_bounds__(256, 2) void gemm_oproj(
    const u16* __restrict__ Xo, const u16* __restrict__ BT, float* __restrict__ out)
{
    __shared__ __align__(16) u16 sA[2][64 * 32];
    __shared__ __align__(16) u16 sB[2][64 * 32];
    const int tid = threadIdx.x;
    const int lane = tid & 63, l31 = lane & 31, lh = lane >> 5;
    const int w = tid >> 6, wrow = w & 1, wcol = w >> 1;
    const int n0 = blockIdx.x * 64, m0 = blockIdx.y * 64;

    // staging: wave w owns rows [16w, 16w+16) of both tiles
    const int rb0 = w * 16;
    const int grow = lane >> 2;
    const int gseg = (lane & 3) * 8;

    auto stage = [&](int b, int kt) {
        gload16(Xo + (long)(m0 + rb0 + grow) * 512 + kt + gseg, &sA[b][rb0 * 32]);
        gload16(BT + (long)(n0 + rb0 + grow) * 512 + kt + gseg, &sB[b][rb0 * 32]);
    };

    floatx16 acc = {0};
    stage(0, 0);
    for (int it = 0; it < 16; ++it) {
        const int cur = it & 1;
        __syncthreads();
        if (it < 15) stage(cur ^ 1, (it + 1) * 32);
        #pragma unroll
        for (int s = 0; s < 2; ++s) {
            const int ko = s * 16 + lh * 8;
            const short8 fa = *(const short8*)(&sA[cur][(wrow * 32 + l31) * 32 + ko]);
            const short8 fb = *(const short8*)(&sB[cur][(wcol * 32 + l31) * 32 + ko]);
            acc = MFMA_BF16(fa, fb, acc);
        }
    }

    const int col = n0 + wcol * 32 + l31;
    #pragma unroll
    for (int reg = 0; reg < 16; ++reg) {
        const int row = m0 + wrow * 32 + (reg & 3) + 8 * (reg >> 2) + 4 * lh;
        out[(long)row * 512 + col] = acc[reg];
    }
}

extern "C" void kernel_launch(void* const* d_in, const int* in_sizes, int n_in,
                              void* d_out, int out_size, void* d_ws, size_t ws_size,
                              hipStream_t stream) {
    const float* xr    = (const float*)d_in[0];
    const float* xi    = (const float*)d_in[1];
    const float* wq_r  = (const float*)d_in[2];
    const float* wq_i  = (const float*)d_in[3];
    const float* wkv_r = (const float*)d_in[4];
    const float* wkv_i = (const float*)d_in[5];
    const float* wo_r  = (const float*)d_in[6];
    const float* wo_i  = (const float*)d_in[7];
    float* out = (float*)d_out;

    u16* ws16 = (u16*)d_ws;
    u16* qr   = ws16 + 0 * kPlane;
    u16* qi   = ws16 + 1 * kPlane;
    u16* kr   = ws16 + 2 * kPlane;
    u16* ki   = ws16 + 3 * kPlane;
    u16* vrT  = ws16 + 4 * kPlane;
    u16* viT  = ws16 + 5 * kPlane;
    u16* xo   = ws16 + 6 * kPlane;               // 2,097,152 elems
    u16* Wbig = ws16 + 8 * kPlane;               // 786,432 elems
    u16* WoT  = Wbig + 786432;                   // 262,144 elems
    u16* Xbf  = xo;    // time-shared: Xbf consumed by gemm_proj before attn writes xo

    prep_w<<<3072, 256, 0, stream>>>(xr, xi, wq_r, wq_i, wkv_r, wkv_i, wo_r, wo_i,
                                     Wbig, WoT, Xbf);
    gemm_proj<<<dim3(12, 32), 256, 0, stream>>>(Xbf, Wbig, qr, qi, kr, ki, vrT, viT);
    attn_kernel<<<dim3(kBH, kN / 64), 256, 0, stream>>>(qr, qi, kr, ki, vrT, viT, xo);
    gemm_oproj<<<dim3(8, 64), 256, 0, stream>>>(xo, WoT, out);
}